// Round 7
// baseline (456.869 us; speedup 1.0000x reference)
//
#include <hip/hip_runtime.h>

// GraphPooling: B=8, N=3072, D=1024, POOL=3, steps=1024
//  out[b, 2k,   d] = (sum x[b, s..e, d]) / (e-s+1) + 0.006
//  out[b, 2k+1, d] = mean(x[b, 3k:3k+3, d])
//
// Round-13 (resubmit; R6 bench was a GPU-acquisition timeout, no data):
// 2-kernel decoupled-lookback pipeline.
//  Evidence: 3 different algorithms all land at 192-195 us; R4 fused counters
//  show whole algorithm = 283 MB HBM (44 us of BW), VALUBusy 1.4% -> the cost
//  is latency + launch structure, not traffic. So: minimize kernels and
//  dependent phases.
//   K0micro: zero 4 KB of flags/tickets (workspace is poisoned).
//   K1 (1024 blocks): per-batch ticket -> chunk id; self-bucket events from
//     the L2-hot 8 KB graph; 24 nt x-loads; publish chunk-total row P + flag
//     (device scope, publish BEFORE any wait -> deadlock-free by ticket
//     order); window means -> out odd rows (overlaps wait); spin on
//     predecessor flags; sum predecessor P rows (L2) -> global offset; walk
//     rows pushing FULL prefix C into T at event rows. Chunk 127 also
//     serves row-N (grand total) events.
//   K4 (2048 blocks): out[2k] = (T[2k+1]-T[2k])*inv + EPS. Pure streaming,
//     no gathers, no selects.

constexpr int Bdim  = 8;
constexpr int Nn    = 3072;
constexpr int Dd    = 1024;
constexpr int STEPS = 1024;   // windows
constexpr int CHW   = 8;      // windows per chunk
constexpr int CHR   = 24;     // rows per chunk
constexpr int NCH   = 128;    // STEPS / CHW
constexpr int KT    = 4;      // steps per K4 block
constexpr int NKT   = 256;    // STEPS / KT
constexpr int D4    = Dd / 4; // 256 float4 per row
constexpr int RCAP  = 16;     // max events per row (R5 passed with 12)
constexpr float EPS = 0.006f;

constexpr size_t T_E = (size_t)Bdim * 2 * STEPS * Dd;     // 64 MB (floats)
constexpr size_t P_E = (size_t)Bdim * NCH * Dd;           //  4 MB

typedef float nat_f4 __attribute__((ext_vector_type(4)));

__device__ __forceinline__ float4 f4add(float4 a, float4 b) {
    return make_float4(a.x + b.x, a.y + b.y, a.z + b.z, a.w + b.w);
}

__device__ __forceinline__ void nt_store(float4 v, float4* p) {
    nat_f4 nv = {v.x, v.y, v.z, v.w};
    __builtin_nontemporal_store(nv, reinterpret_cast<nat_f4*>(p));
}

__device__ __forceinline__ float4 nt_load(const float4* p) {
    nat_f4 nv = __builtin_nontemporal_load(reinterpret_cast<const nat_f4*>(p));
    return make_float4(nv.x, nv.y, nv.z, nv.w);
}

// ---------------- K0micro: zero flags + tickets (4.1 KB) ----------------
__global__ __launch_bounds__(256)
void k0_zero(int* __restrict__ flags, int* __restrict__ tick) {
    const int t = threadIdx.x;
    for (int i = t; i < Bdim * NCH; i += 256) flags[i] = 0;
    if (t < Bdim) tick[t] = 0;
}

// ---------------- K1: ticketed scan + lookback + snapshot push ----------
__global__ __launch_bounds__(256)
void k1_scan(const float4* __restrict__ x4, const int* __restrict__ graph,
             float4* __restrict__ out4, float4* __restrict__ T4,
             float4* __restrict__ P4, int* __restrict__ flags,
             int* __restrict__ tick) {
    const int t = threadIdx.x;           // float4 column 0..255
    const int b = blockIdx.y;            // 0..7
    const float4 z4 = make_float4(0.f, 0.f, 0.f, 0.f);

    // ---- ticket: chunk id in scheduling order (deadlock-free lookback) ----
    __shared__ int s_tk;
    if (t == 0) s_tk = atomicAdd(&tick[b], 1);
    __syncthreads();
    const int tk = s_tk;                 // 0..127
    const int r0 = tk * CHR;
    const int k0 = tk * CHW;

    // ---- self-bucket: find events (query rows) in [r0, r0+24] ----
    __shared__ int cnt[CHR + 1];
    __shared__ int lst[CHR + 1][RCAP];
    for (int i = t; i < CHR + 1; i += 256) cnt[i] = 0;
    __syncthreads();
    for (int k = t; k < STEPS; k += 256) {
        const int2 se = *reinterpret_cast<const int2*>(
            graph + ((size_t)(b * STEPS + k)) * 2);
        const int js = se.x - r0;                // start snapshot row
        if (js >= 0 && js < CHR) {
            int p = atomicAdd(&cnt[js], 1);
            if (p < RCAP) lst[js][p] = 2 * k;
        }
        const int je = se.y + 1 - r0;            // end snapshot row
        if (je >= 0 && (je < CHR || (je == CHR && tk == NCH - 1))) {
            int p = atomicAdd(&cnt[je], 1);
            if (p < RCAP) lst[je][p] = 2 * k + 1;
        }
    }
    __syncthreads();

    // ---- load 24 x rows (nt) + sequential chunk total ----
    const float4* xp = x4 + ((size_t)(b * Nn + r0)) * D4 + t;
    float4 v[CHR];
#pragma unroll
    for (int i = 0; i < CHR; ++i)
        v[i] = nt_load(&xp[(size_t)i * D4]);

    float4 tot = z4;
#pragma unroll
    for (int i = 0; i < CHR; ++i) tot = f4add(tot, v[i]);

    // ---- publish aggregate row + flag (BEFORE any waiting) ----
    P4[((size_t)b * NCH + tk) * D4 + t] = tot;
    __threadfence();                     // order my stores device-wide
    __syncthreads();                     // all threads' fences done
    if (t == 0)
        __hip_atomic_store(&flags[b * NCH + tk], 1,
                           __ATOMIC_RELEASE, __HIP_MEMORY_SCOPE_AGENT);

    // ---- window means -> odd out rows (independent work overlaps wait) ----
    float4* op = out4 + ((size_t)b * 2 * STEPS) * D4 + t;
#pragma unroll
    for (int wi = 0; wi < CHW; ++wi) {
        float4 w = f4add(f4add(v[3 * wi], v[3 * wi + 1]), v[3 * wi + 2]);
        float4 wm = make_float4(w.x * (1.f / 3.f), w.y * (1.f / 3.f),
                                w.z * (1.f / 3.f), w.w * (1.f / 3.f));
        nt_store(wm, &op[(size_t)(2 * (k0 + wi) + 1) * D4]);
    }

    // ---- wait for all predecessors' aggregates ----
    if (t < tk) {
        const int* fp = &flags[b * NCH + t];
        while (__hip_atomic_load(fp, __ATOMIC_ACQUIRE,
                                 __HIP_MEMORY_SCOPE_AGENT) == 0)
            __builtin_amdgcn_s_sleep(2);
    }
    __syncthreads();

    // ---- lookback: exclusive global offset = sum of P[0..tk-1] (L2) ----
    float4 off = z4;
    const float4* pb = P4 + (size_t)b * NCH * D4 + t;
    for (int i = 0; i < tk; ++i)
        off = f4add(off, pb[(size_t)i * D4]);

    // ---- walk rows, pushing FULL prefix C at event rows ----
    float4* Tb = T4 + ((size_t)b * 2 * STEPS) * D4 + t;
    float4 run = off;
#pragma unroll
    for (int j = 0; j < CHR; ++j) {
        const int nj = min(cnt[j], RCAP);
        for (int q = 0; q < nj; ++q)               // usually 0 or 1
            Tb[(size_t)lst[j][q] * D4] = run;      // coalesced 4 KB row
        run = f4add(run, v[j]);
    }
    if (tk == NCH - 1) {                            // row N: grand total
        const int nj = min(cnt[CHR], RCAP);
        for (int q = 0; q < nj; ++q)
            Tb[(size_t)lst[CHR][q] * D4] = run;
    }
}

// ---------------- K4: pure streaming combine ----------------
//  out[2k] = (T[2k+1] - T[2k]) * inv + EPS
__global__ __launch_bounds__(256)
void k4_combine(const float4* __restrict__ T4, const int* __restrict__ graph,
                float4* __restrict__ out4) {
    const int t  = threadIdx.x;
    const int kt = blockIdx.x;                 // 0..255
    const int b  = blockIdx.y;

    const int* gp = graph + ((size_t)(b * STEPS + kt * KT)) * 2;
    const int4 ga = *reinterpret_cast<const int4*>(gp);
    const int4 gb = *reinterpret_cast<const int4*>(gp + 4);
    const int sA[KT] = {ga.x, ga.z, gb.x, gb.z};
    const int eA[KT] = {ga.y, ga.w, gb.y, gb.w};

    const float4* Tb = T4 + (size_t)b * 2 * STEPS * D4 + t;
    float4*       ob = out4 + (size_t)b * 2 * STEPS * D4 + t;

    // sequential T rows 2*kbase .. 2*kbase+7: contiguous 32 KB per block
    float4 ts[KT], te[KT];
#pragma unroll
    for (int u = 0; u < KT; ++u) {
        const int k = kt * KT + u;
        ts[u] = Tb[(size_t)(2 * k) * D4];
        te[u] = Tb[(size_t)(2 * k + 1) * D4];
    }

#pragma unroll
    for (int u = 0; u < KT; ++u) {
        const float inv = 1.f / (float)(eA[u] - sA[u] + 1);
        float4 res = make_float4((te[u].x - ts[u].x) * inv + EPS,
                                 (te[u].y - ts[u].y) * inv + EPS,
                                 (te[u].z - ts[u].z) * inv + EPS,
                                 (te[u].w - ts[u].w) * inv + EPS);
        const int k = kt * KT + u;
        nt_store(res, &ob[(size_t)(2 * k) * D4]);   // even output row
    }
}

extern "C" void kernel_launch(void* const* d_in, const int* in_sizes, int n_in,
                              void* d_out, int out_size, void* d_ws, size_t ws_size,
                              hipStream_t stream) {
    const float* x     = (const float*)d_in[0];
    const int*   graph = (const int*)d_in[1];
    float*       out   = (float*)d_out;

    float* T = (float*)d_ws;
    float* P = T + T_E;
    int*   flags = (int*)(P + P_E);
    int*   tick  = flags + (size_t)Bdim * NCH;

    k0_zero<<<dim3(1), 256, 0, stream>>>(flags, tick);
    dim3 g1(NCH, Bdim);          // (128, 8) = 1024 blocks
    k1_scan<<<g1, 256, 0, stream>>>((const float4*)x, graph, (float4*)out,
                                    (float4*)T, (float4*)P, flags, tick);
    dim3 g4(NKT, Bdim);          // (256, 8) = 2048 blocks
    k4_combine<<<g4, 256, 0, stream>>>((const float4*)T, graph, (float4*)out);
}

// Round 8
// 182.276 us; speedup vs baseline: 2.5065x; 2.5065x over previous
//
#include <hip/hip_runtime.h>

// GraphPooling: B=8, N=3072, D=1024, POOL=3, steps=1024
//  out[b, 2k,   d] = (sum x[b, s..e, d]) / (e-s+1) + 0.006
//  out[b, 2k+1, d] = mean(x[b, 3k:3k+3, d])
//
// Round-14: 3-kernel event-push (R5 structure, K0 folded into K1).
//  R7 post-mortem: decoupled-lookback spin (agent-scope acquire loads) =
//  cache-invalidate storm -> k1 316 us, 6.7% HBM. Cross-XCD spin is dead.
//  R5 (193 us) had a hidden flaw: K0 bucketing ran on 8 blocks (3% of
//  machine, ~20 us latency-bound + a launch gap). R7 proved per-block
//  self-bucketing inside the 1024-block scan kernel works. So:
//   K1 (128x8 blocks): self-bucket events for own 25 rows from L2-hot 8 KB
//       graph (LDS atomics); 24 nt x-loads; window means -> odd out rows;
//       within-chunk exclusive prefix, pushing snapshots into dense T at
//       event rows; chunk total -> P.
//   K2 (64 blocks): proven 2-level scan P -> exclusive chunk prefix O.
//   K4 (2048 blocks): out[2k] = (O[ch(e+1)]+T[2k+1]-O[ch(s)]-T[2k])*inv+EPS;
//       T read sequentially; O rows L2/L3-hot; ie==Nn -> grand-total row.
//  Same summation order as R5 -> absmax 0.00195 expected.

constexpr int Bdim  = 8;
constexpr int Nn    = 3072;
constexpr int Dd    = 1024;
constexpr int STEPS = 1024;   // windows
constexpr int CHW   = 8;      // windows per chunk
constexpr int CHR   = 24;     // rows per chunk
constexpr int NCH   = 128;    // STEPS / CHW
constexpr int KT    = 4;      // steps per K4 block
constexpr int NKT   = 256;    // STEPS / KT
constexpr int D4    = Dd / 4; // 256 float4 per row
constexpr int RCAP  = 16;     // max events per row (R5 passed with 12)
constexpr float EPS = 0.006f;

constexpr size_t T_E = (size_t)Bdim * 2 * STEPS * Dd;     // 64 MB (floats)
constexpr size_t P_E = (size_t)Bdim * NCH * Dd;           //  4 MB

typedef float nat_f4 __attribute__((ext_vector_type(4)));

__device__ __forceinline__ float4 f4add(float4 a, float4 b) {
    return make_float4(a.x + b.x, a.y + b.y, a.z + b.z, a.w + b.w);
}

__device__ __forceinline__ float4 f4sel(bool c, float4 a, float4 b) {
    return make_float4(c ? a.x : b.x, c ? a.y : b.y,
                       c ? a.z : b.z, c ? a.w : b.w);
}

__device__ __forceinline__ void nt_store(float4 v, float4* p) {
    nat_f4 nv = {v.x, v.y, v.z, v.w};
    __builtin_nontemporal_store(nv, reinterpret_cast<nat_f4*>(p));
}

__device__ __forceinline__ float4 nt_load(const float4* p) {
    nat_f4 nv = __builtin_nontemporal_load(reinterpret_cast<const nat_f4*>(p));
    return make_float4(nv.x, nv.y, nv.z, nv.w);
}

// ---------------- K1: self-bucket + scan + window means + snapshot push ----
__global__ __launch_bounds__(256)
void k1_scan(const float4* __restrict__ x4, const int* __restrict__ graph,
             float4* __restrict__ out4, float4* __restrict__ T4,
             float4* __restrict__ P4) {
    const int t  = threadIdx.x;          // float4 column 0..255
    const int ch = blockIdx.x;           // 0..127
    const int b  = blockIdx.y;           // 0..7
    const int k0 = ch * CHW;
    const int r0 = ch * CHR;
    const float4 z4 = make_float4(0.f, 0.f, 0.f, 0.f);

    // ---- issue the 24 x row loads first (latency overlaps bucketing) ----
    const float4* xp = x4 + ((size_t)(b * Nn + r0)) * D4 + t;
    float4 v[CHR];
#pragma unroll
    for (int i = 0; i < CHR; ++i)
        v[i] = nt_load(&xp[(size_t)i * D4]);

    // ---- self-bucket: events (query rows) landing in [r0, r0+CHR) ----
    //  row s   -> trow 2k (start snapshot); row e+1 -> trow 2k+1 (end),
    //  e+1 == Nn handled in K4 via the grand-total row.
    __shared__ int cnt[CHR];
    __shared__ int lst[CHR][RCAP];
    if (t < CHR) cnt[t] = 0;
    __syncthreads();
    for (int k = t; k < STEPS; k += 256) {
        const int2 se = *reinterpret_cast<const int2*>(
            graph + ((size_t)(b * STEPS + k)) * 2);
        const int js = se.x - r0;                // start snapshot row
        if (js >= 0 && js < CHR) {
            int p = atomicAdd(&cnt[js], 1);
            if (p < RCAP) lst[js][p] = 2 * k;
        }
        const int je = se.y + 1 - r0;            // end snapshot row
        if (je >= 0 && je < CHR) {
            int p = atomicAdd(&cnt[je], 1);
            if (p < RCAP) lst[je][p] = 2 * k + 1;
        }
    }
    __syncthreads();

    // ---- window means -> odd output rows ----
    float4* op = out4 + ((size_t)b * 2 * STEPS) * D4 + t;
#pragma unroll
    for (int wi = 0; wi < CHW; ++wi) {
        float4 w = f4add(f4add(v[3 * wi], v[3 * wi + 1]), v[3 * wi + 2]);
        float4 wm = make_float4(w.x * (1.f / 3.f), w.y * (1.f / 3.f),
                                w.z * (1.f / 3.f), w.w * (1.f / 3.f));
        nt_store(wm, &op[(size_t)(2 * (k0 + wi) + 1) * D4]);
    }

    // ---- within-chunk exclusive prefix; push snapshots at event rows ----
    float4* Tb = T4 + ((size_t)b * 2 * STEPS) * D4 + t;
    float4 run = z4;
#pragma unroll
    for (int j = 0; j < CHR; ++j) {
        const int nj = min(cnt[j], RCAP);        // uniform (LDS broadcast)
        for (int q = 0; q < nj; ++q)             // usually 0 or 1
            Tb[(size_t)lst[j][q] * D4] = run;    // coalesced 4 KB row
        run = f4add(run, v[j]);
    }
    P4[((size_t)b * NCH + ch) * D4 + t] = run;   // chunk total
}

// ---------------- K2: 2-level scan of chunk totals -> exclusive prefix O ----
__global__ __launch_bounds__(256)
void k2_chscan(const float4* __restrict__ P4, float4* __restrict__ O4) {
    __shared__ float4 part[8][33];
    const int cw  = threadIdx.x & 31;          // f4-col within tile
    const int seg = threadIdx.x >> 5;          // 0..7 -> 16 chunks each
    const int col = blockIdx.x * 32 + cw;
    const int b   = blockIdx.y;

    const float4* p = P4 + (size_t)b * NCH * D4 + col;
    float4 v[16];
    float4 sum = make_float4(0.f, 0.f, 0.f, 0.f);
#pragma unroll
    for (int i = 0; i < 16; ++i) {
        v[i] = p[(size_t)(seg * 16 + i) * D4];
        sum = f4add(sum, v[i]);
    }
    part[seg][cw] = sum;
    __syncthreads();
    if (threadIdx.x < 32) {
        float4 run = make_float4(0.f, 0.f, 0.f, 0.f);
#pragma unroll
        for (int s = 0; s < 8; ++s) {
            float4 t2 = part[s][threadIdx.x];
            part[s][threadIdx.x] = run;
            run = f4add(run, t2);
        }
    }
    __syncthreads();
    float4 run = part[seg][cw];
    float4* o = O4 + (size_t)b * (NCH + 1) * D4 + col;
#pragma unroll
    for (int i = 0; i < 16; ++i) {
        o[(size_t)(seg * 16 + i) * D4] = run;
        run = f4add(run, v[i]);
    }
    if (seg == 7) o[(size_t)NCH * D4] = run;   // grand total = c[N]
}

// ---------------- K4: streaming combine ----------------
//  out[2k] = (O[ch(e+1)] + T[2k+1] - O[ch(s)] - T[2k]) * inv + EPS
__global__ __launch_bounds__(256)
void k4_combine(const float4* __restrict__ T4, const float4* __restrict__ O4,
                const int* __restrict__ graph, float4* __restrict__ out4) {
    const int t  = threadIdx.x;
    const int kt = blockIdx.x;                 // 0..255
    const int b  = blockIdx.y;

    const int* gp = graph + ((size_t)(b * STEPS + kt * KT)) * 2;
    const int4 ga = *reinterpret_cast<const int4*>(gp);
    const int4 gb = *reinterpret_cast<const int4*>(gp + 4);
    const int sA[KT] = {ga.x, ga.z, gb.x, gb.z};
    const int eA[KT] = {ga.y, ga.w, gb.y, gb.w};

    const float4* Tb = T4 + (size_t)b * 2 * STEPS * D4 + t;
    const float4* oc = O4 + (size_t)b * (NCH + 1) * D4 + t;
    float4*       ob = out4 + (size_t)b * 2 * STEPS * D4 + t;

    // ---- issue ALL loads before any combine ----
    float4 ts[KT], te[KT], o1[KT], o2[KT];
    int ieA[KT];
    const float4 tot = oc[(size_t)NCH * D4];   // grand total row (hot)
#pragma unroll
    for (int u = 0; u < KT; ++u) {
        const int k = kt * KT + u;
        ts[u] = Tb[(size_t)(2 * k) * D4];      // sequential streaming rows
        te[u] = Tb[(size_t)(2 * k + 1) * D4];
        const int s = sA[u];
        const int ie = eA[u] + 1;  ieA[u] = ie;            // 1..3072
        o1[u] = oc[(size_t)(s / CHR) * D4];                // hot 4.2 MB table
        const int c2 = ie < Nn ? ie / CHR : 0;             // clamp (sel'd away)
        o2[u] = oc[(size_t)c2 * D4];
    }

    // ---- combine + store ----
#pragma unroll
    for (int u = 0; u < KT; ++u) {
        float4 cs = f4add(o1[u], ts[u]);
        float4 ce = f4sel(ieA[u] < Nn, f4add(o2[u], te[u]), tot);

        float inv = 1.f / (float)(eA[u] - sA[u] + 1);
        float4 res = make_float4((ce.x - cs.x) * inv + EPS,
                                 (ce.y - cs.y) * inv + EPS,
                                 (ce.z - cs.z) * inv + EPS,
                                 (ce.w - cs.w) * inv + EPS);
        const int k = kt * KT + u;
        nt_store(res, &ob[(size_t)(2 * k) * D4]);   // even output row
    }
}

extern "C" void kernel_launch(void* const* d_in, const int* in_sizes, int n_in,
                              void* d_out, int out_size, void* d_ws, size_t ws_size,
                              hipStream_t stream) {
    const float* x     = (const float*)d_in[0];
    const int*   graph = (const int*)d_in[1];
    float*       out   = (float*)d_out;

    float* T = (float*)d_ws;
    float* P = T + T_E;
    float* O = P + P_E;

    dim3 g1(NCH, Bdim);          // (128, 8) = 1024 blocks
    k1_scan<<<g1, 256, 0, stream>>>((const float4*)x, graph, (float4*)out,
                                    (float4*)T, (float4*)P);
    dim3 g2(D4 / 32, Bdim);      // (8, 8) = 64 blocks
    k2_chscan<<<g2, 256, 0, stream>>>((const float4*)P, (float4*)O);
    dim3 g4(NKT, Bdim);          // (256, 8) = 2048 blocks
    k4_combine<<<g4, 256, 0, stream>>>((const float4*)T, (const float4*)O,
                                       graph, (float4*)out);
}